// Round 3
// baseline (933.216 us; speedup 1.0000x reference)
//
#include <hip/hip_runtime.h>
#include <cstddef>

#define NB 4096
#define NT 64
#define NOBS 64
#define NH 64
#define NA 8
#define NS 201

// d_out layout (floats):
//   logits [B,T,A]  @ 0          (2097152)
//   values [T*B]    @ 2097152    (262144)
//   stack  [B,S,H]  @ 2359296    (52690944)
//   ptrs   [B]      @ 55050240   (4096, stored as float)

// Broadcast lane k's value to all lanes via v_readlane (SGPR path, VALU pipe —
// no LDS). k must be a compile-time constant (unrolled loops below).
__device__ __forceinline__ float bl(float v, int k) {
    return __int_as_float(__builtin_amdgcn_readlane(__float_as_int(v), k));
}

__launch_bounds__(128, 2)
__global__ void stacknet_kernel(const float* __restrict__ x,
                                const float* __restrict__ stack_in,
                                const int* __restrict__ ptrs_in,
                                const float* __restrict__ W1,
                                const float* __restrict__ b1,
                                const float* __restrict__ W2,
                                const float* __restrict__ b2,
                                const float* __restrict__ Ws,
                                const float* __restrict__ bs,
                                const float* __restrict__ Wp,
                                const float* __restrict__ bp,
                                const float* __restrict__ Wv,
                                const float* __restrict__ bv,
                                float* __restrict__ logits_out,
                                float* __restrict__ values_out,
                                float* __restrict__ stack,
                                float* __restrict__ ptrs_out) {
    const int lane = threadIdx.x & 63;
    const int wv   = threadIdx.x >> 6;           // 0..1 (2 waves/block)
    const int b    = (blockIdx.x << 1) + wv;     // batch element = wave
    const int aa   = lane & 15;                  // head index (0..11 valid)

    // Per-wave XC table: XC[t][i] = sum_{k<64} x[t][k]*W1[i][k]  (NO b1 —
    // b1 is added at the end of stage A so the full 128-FMA chain is
    // bit-identical to the reference kernel's single sequential chain).
    __shared__ __align__(16) float xcl[2][NT * NH];   // 32 KB

    const float* xb = x + (size_t)b * NT * NOBS;
    float* stk      = stack + (size_t)b * NS * NH;

    // ---- Phase 1: copy this batch's stack slab in -> out (wave-private). ----
    {
        const float4* s4 = (const float4*)(stack_in + (size_t)b * (NS * NH));
        float4* d4 = (float4*)stk;
#pragma unroll 4
        for (int i = lane; i < (NS * NH / 4); i += 64) d4[i] = s4[i];
    }

    // ---- Phase 2: XC table. Per t: coalesced x load, then sequential-k
    //      chain (k=0..63 ascending, acc starts at 0) == first half of the
    //      original 128-FMA stage-A chain. ----
    {
        float w1x[64];
#pragma unroll
        for (int j = 0; j < 16; ++j) {
            float4 w = ((const float4*)W1)[lane * 32 + j];     // row lane, cols 4j..
            w1x[4*j] = w.x; w1x[4*j+1] = w.y; w1x[4*j+2] = w.z; w1x[4*j+3] = w.w;
        }
        float* xcw = xcl[wv];
        float xv = xb[lane];                                   // t=0 prefetch
#pragma unroll 1
        for (int t = 0; t < NT; ++t) {
            float xnext = (t + 1 < NT) ? xb[(t + 1) * 64 + lane] : 0.f;
            float acc = 0.f;
#pragma unroll
            for (int k = 0; k < 64; ++k) acc = fmaf(w1x[k], bl(xv, k), acc);
            xcw[t * 64 + lane] = acc;
            xv = xnext;
        }
    }   // w1x dead -> registers reused below

    // ---- Phase 3: persistent weights in registers ----
    float w1h[64], w2r[64], hw[64];
#pragma unroll
    for (int j = 0; j < 16; ++j) {
        float4 wa = ((const float4*)W1)[lane * 32 + 16 + j];   // row lane, cols 64+4j
        w1h[4*j] = wa.x; w1h[4*j+1] = wa.y; w1h[4*j+2] = wa.z; w1h[4*j+3] = wa.w;
        float4 wb = ((const float4*)W2)[lane * 16 + j];        // row lane
        w2r[4*j] = wb.x; w2r[4*j+1] = wb.y; w2r[4*j+2] = wb.z; w2r[4*j+3] = wb.w;
    }
    if (aa < 12) {
        const float* hsrc = (aa < 3) ? (Ws + aa * 64)
                          : (aa < 11) ? (Wp + (aa - 3) * 64) : Wv;
#pragma unroll
        for (int j = 0; j < 16; ++j) {
            float4 w = *(const float4*)(hsrc + 4 * j);
            hw[4*j] = w.x; hw[4*j+1] = w.y; hw[4*j+2] = w.z; hw[4*j+3] = w.w;
        }
    } else {
#pragma unroll
        for (int k = 0; k < 64; ++k) hw[k] = 0.f;
    }
    float b1r  = b1[lane];
    float b2r  = b2[lane];
    float shba = (aa < 3) ? bs[aa] : (aa < 11) ? bp[aa - 3] : (aa == 11) ? bv[0] : 0.f;

    // Drain slab-copy stores (and weight loads) before the t-loop reads the slab.
    asm volatile("s_waitcnt vmcnt(0)" ::: "memory");

    int ptr   = ptrs_in[b];
    float top = stk[ptr * 64 + lane];
    // 2-deep store-forwarding for recently pushed rows (own stores may not
    // have drained to L2 by the time we re-read them).
    int   lastRow = -1, lastRow2 = -1;
    float lastVal = 0.f, lastVal2 = 0.f;

    const float* xcw = xcl[wv];
    float* lgb = logits_out + (size_t)b * NT * NA;

#pragma unroll 1
    for (int t = 0; t < NT; ++t) {
        // Prefetch pop/push candidates + this step's xc.
        int r0    = (ptr > 0) ? (ptr - 1) : 0;
        float c0  = stk[r0 * 64 + lane];
        float c2  = stk[(ptr + 1) * 64 + lane];
        float xcv = xcw[t * 64 + lane];

        // ---- stage A: h = tanh( [chain k=0..63 over x (== xcv)] continued
        //      by chain k=64..127 over top, + b1 at end ). Bit-exact vs the
        //      original single 128-FMA chain. ----
        float acc = xcv;
#pragma unroll
        for (int k = 0; k < 64; ++k) acc = fmaf(w1h[k], bl(top, k), acc);
        float h = tanhf(acc + b1r);

        // ---- stage B: p = tanh( chain k=0..63 over h, + b2 ) ----
        float acc2 = 0.f;
#pragma unroll
        for (int k = 0; k < 64; ++k) acc2 = fmaf(w2r[k], bl(h, k), acc2);
        float p = tanhf(acc2 + b2r);

        // ---- stage C: head aa, single sequential chain over p ----
        float hacc = 0.f;
#pragma unroll
        for (int k = 0; k < 64; ++k) hacc = fmaf(hw[k], bl(p, k), hacc);
        float sv = hacc + shba;

        // ---- decision (wave-uniform), softmax mimic, first strict max ----
        float s0 = bl(sv, 0), s1 = bl(sv, 1), s2 = bl(sv, 2);
        float mx = fmaxf(fmaxf(s0, s1), s2);
        float e0 = expf(s0 - mx), e1 = expf(s1 - mx), e2 = expf(s2 - mx);
        float S = (e0 + e1) + e2;
        float q0 = e0 / S, q1 = e1 / S, q2 = e2 / S;
        int op = 0; float pm = q0;
        if (q1 > pm) { pm = q1; op = 1; }
        if (q2 > pm) { op = 2; }

        if (op == 2) stk[ptr * 64 + lane] = p;

        // Next top with 2-deep forwarding (newest entry checked first).
        float sel;
        if (op == 0) {
            sel = (r0 == lastRow) ? lastVal
                : (r0 == lastRow2) ? lastVal2 : c0;
        } else if (op == 1) {
            sel = top;
        } else {
            int r2 = ptr + 1;
            sel = (r2 == lastRow) ? lastVal
                : (r2 == lastRow2) ? lastVal2 : c2;
        }
        if (op == 2) { lastRow2 = lastRow; lastVal2 = lastVal;
                       lastRow = ptr;      lastVal  = p; }

        int np = ptr + op - 1;
        ptr = (np < 0) ? 0 : np;
        top = sel;

        // ---- outputs: lanes 3..10 -> logits, lane 11 -> value ----
        if (lane >= 3 && lane <= 10) lgb[t * NA + (lane - 3)] = sv;
        if (lane == 11) values_out[(size_t)t * NB + b] = sv;
    }
    if (lane == 0) ptrs_out[b] = (float)ptr;
}

extern "C" void kernel_launch(void* const* d_in, const int* in_sizes, int n_in,
                              void* d_out, int out_size, void* d_ws, size_t ws_size,
                              hipStream_t stream) {
    const float* x        = (const float*)d_in[0];
    const float* stack_in = (const float*)d_in[1];
    const int*   ptrs_in  = (const int*)d_in[2];
    const float* W1 = (const float*)d_in[3];
    const float* b1 = (const float*)d_in[4];
    const float* W2 = (const float*)d_in[5];
    const float* b2 = (const float*)d_in[6];
    const float* Ws = (const float*)d_in[7];
    const float* bs = (const float*)d_in[8];
    const float* Wp = (const float*)d_in[9];
    const float* bp = (const float*)d_in[10];
    const float* Wv = (const float*)d_in[11];
    const float* bv = (const float*)d_in[12];

    float* out      = (float*)d_out;
    float* logits   = out;                 // 2097152
    float* values   = out + 2097152;       // 262144
    float* stack    = out + 2359296;       // 52690944
    float* ptrs_out = out + 55050240;      // 4096

    stacknet_kernel<<<NB / 2, 128, 0, stream>>>(x, stack_in, ptrs_in,
                                                W1, b1, W2, b2, Ws, bs,
                                                Wp, bp, Wv, bv,
                                                logits, values, stack, ptrs_out);
}

// Round 4
// 720.954 us; speedup vs baseline: 1.2944x; 1.2944x over previous
//
#include <hip/hip_runtime.h>
#include <cstddef>

#define NB 4096
#define NT 64
#define NOBS 64
#define NH 64
#define NA 8
#define NS 201

// d_out layout (floats):
//   logits [B,T,A]  @ 0          (2097152)
//   values [T*B]    @ 2097152    (262144)
//   stack  [B,S,H]  @ 2359296    (52690944)
//   ptrs   [B]      @ 55050240   (4096, stored as float)

// Broadcast lane k's value via v_readlane (used ONLY in phase 2, where the
// chains across t are independent and pipeline; the recurrent loop uses LDS
// broadcast which measured 1.8x faster end-to-end).
__device__ __forceinline__ float bl(float v, int k) {
    return __int_as_float(__builtin_amdgcn_readlane(__float_as_int(v), k));
}

__launch_bounds__(64, 2)
__global__ void stacknet_kernel(const float* __restrict__ x,
                                const float* __restrict__ stack_in,
                                const int* __restrict__ ptrs_in,
                                const float* __restrict__ W1,
                                const float* __restrict__ b1,
                                const float* __restrict__ W2,
                                const float* __restrict__ b2,
                                const float* __restrict__ Ws,
                                const float* __restrict__ bs,
                                const float* __restrict__ Wp,
                                const float* __restrict__ bp,
                                const float* __restrict__ Wv,
                                const float* __restrict__ bv,
                                float* __restrict__ logits_out,
                                float* __restrict__ values_out,
                                float* __restrict__ stack,
                                float* __restrict__ ptrs_out) {
    const int lane = threadIdx.x;        // 1 wave per block
    const int b    = blockIdx.x;         // batch element = block
    const int aa   = lane & 15;          // head index (0..11 valid)

    // XC[t][i] = sum_{k<64} x[t][k]*W1[i][k]  (fp32-exact prefix of the
    // original 128-FMA stage-A chain; b1 added at the end of stage A).
    __shared__ float xcl[NT * NH];                  // 16 KB
    // [0..63]=top, [64..127]=h, [128..191]=p
    __shared__ __align__(16) float vbuf[192];

    const float* xb = x + (size_t)b * NT * NOBS;
    float* stk      = stack + (size_t)b * NS * NH;

    // ---- Phase 1: copy this batch's stack slab in -> out (wave-private). ----
    {
        const float4* s4 = (const float4*)(stack_in + (size_t)b * (NS * NH));
        float4* d4 = (float4*)stk;
#pragma unroll 4
        for (int i = lane; i < (NS * NH / 4); i += 64) d4[i] = s4[i];
    }

    // ---- Phase 2: XC table via readlane chains (k=0..63 ascending, acc
    //      starts at 0 — identical FMA sequence to the original kernel's
    //      first 64 steps). Independent chains across t pipeline fine. ----
    {
        float w1x[64];
#pragma unroll
        for (int j = 0; j < 16; ++j) {
            float4 w = ((const float4*)W1)[lane * 32 + j];     // row lane, cols 4j..
            w1x[4*j] = w.x; w1x[4*j+1] = w.y; w1x[4*j+2] = w.z; w1x[4*j+3] = w.w;
        }
        float xv = xb[lane];                                   // t=0 prefetch
#pragma unroll 1
        for (int t = 0; t < NT; ++t) {
            float xnext = (t + 1 < NT) ? xb[(t + 1) * 64 + lane] : 0.f;
            float acc = 0.f;
#pragma unroll
            for (int k = 0; k < 64; ++k) acc = fmaf(w1x[k], bl(xv, k), acc);
            xcl[t * 64 + lane] = acc;
            xv = xnext;
        }
    }   // w1x dead -> registers reused below

    // ---- Phase 3: persistent weights in registers ----
    float w1h[64], w2r[64], hw[64];
#pragma unroll
    for (int j = 0; j < 16; ++j) {
        float4 wa = ((const float4*)W1)[lane * 32 + 16 + j];   // row lane, cols 64+4j
        w1h[4*j] = wa.x; w1h[4*j+1] = wa.y; w1h[4*j+2] = wa.z; w1h[4*j+3] = wa.w;
        float4 wb = ((const float4*)W2)[lane * 16 + j];        // row lane
        w2r[4*j] = wb.x; w2r[4*j+1] = wb.y; w2r[4*j+2] = wb.z; w2r[4*j+3] = wb.w;
    }
    if (aa < 12) {
        const float* hsrc = (aa < 3) ? (Ws + aa * 64)
                          : (aa < 11) ? (Wp + (aa - 3) * 64) : Wv;
#pragma unroll
        for (int j = 0; j < 16; ++j) {
            float4 w = *(const float4*)(hsrc + 4 * j);
            hw[4*j] = w.x; hw[4*j+1] = w.y; hw[4*j+2] = w.z; hw[4*j+3] = w.w;
        }
    } else {
#pragma unroll
        for (int k = 0; k < 64; ++k) hw[k] = 0.f;
    }
    float b1r  = b1[lane];
    float b2r  = b2[lane];
    float shba = (aa < 3) ? bs[aa] : (aa < 11) ? bp[aa - 3] : (aa == 11) ? bv[0] : 0.f;

    // Drain slab-copy stores before the t-loop reads the slab.
    asm volatile("s_waitcnt vmcnt(0)" ::: "memory");

    int ptr   = ptrs_in[b];
    float top = stk[ptr * 64 + lane];
    // 2-deep store-forwarding for recently pushed rows.
    int   lastRow = -1, lastRow2 = -1;
    float lastVal = 0.f, lastVal2 = 0.f;

    float* v = vbuf;
    float* lgb = logits_out + (size_t)b * NT * NA;

#pragma unroll 1
    for (int t = 0; t < NT; ++t) {
        // Prefetch pop/push candidates + this step's xc.
        int r0    = (ptr > 0) ? (ptr - 1) : 0;
        float c0  = stk[r0 * 64 + lane];
        float c2  = stk[(ptr + 1) * 64 + lane];
        float xcv = xcl[t * 64 + lane];

        // ---- stage A: continue the 128-chain at k=64 over top, +b1 ----
        v[lane] = top;
        float acc = xcv;
        {
            const float4* v4 = (const float4*)v;
#pragma unroll
            for (int j = 0; j < 16; ++j) {
                float4 a4 = v4[j];                  // same-addr broadcast read
                acc = fmaf(w1h[4*j],   a4.x, acc);
                acc = fmaf(w1h[4*j+1], a4.y, acc);
                acc = fmaf(w1h[4*j+2], a4.z, acc);
                acc = fmaf(w1h[4*j+3], a4.w, acc);
            }
        }
        float h = tanhf(acc + b1r);

        // ---- stage B: p = tanh( chain k=0..63 over h, +b2 ) ----
        v[64 + lane] = h;
        float acc2 = 0.f;
        {
            const float4* h4 = (const float4*)(v + 64);
#pragma unroll
            for (int j = 0; j < 16; ++j) {
                float4 a4 = h4[j];
                acc2 = fmaf(w2r[4*j],   a4.x, acc2);
                acc2 = fmaf(w2r[4*j+1], a4.y, acc2);
                acc2 = fmaf(w2r[4*j+2], a4.z, acc2);
                acc2 = fmaf(w2r[4*j+3], a4.w, acc2);
            }
        }
        float p = tanhf(acc2 + b2r);

        // ---- stage C: head aa, sequential chain over p (hw in regs) ----
        v[128 + lane] = p;
        float hacc = 0.f;
        {
            const float4* p4 = (const float4*)(v + 128);
#pragma unroll
            for (int j = 0; j < 16; ++j) {
                float4 a4 = p4[j];
                hacc = fmaf(a4.x, hw[4*j],   hacc);
                hacc = fmaf(a4.y, hw[4*j+1], hacc);
                hacc = fmaf(a4.z, hw[4*j+2], hacc);
                hacc = fmaf(a4.w, hw[4*j+3], hacc);
            }
        }
        float sv = hacc + shba;

        // ---- decision (wave-uniform), softmax mimic, first strict max ----
        float s0 = __shfl(sv, 0, 64), s1 = __shfl(sv, 1, 64), s2 = __shfl(sv, 2, 64);
        float mx = fmaxf(fmaxf(s0, s1), s2);
        float e0 = expf(s0 - mx), e1 = expf(s1 - mx), e2 = expf(s2 - mx);
        float S = (e0 + e1) + e2;
        float q0 = e0 / S, q1 = e1 / S, q2 = e2 / S;
        int op = 0; float pm = q0;
        if (q1 > pm) { pm = q1; op = 1; }
        if (q2 > pm) { op = 2; }

        if (op == 2) stk[ptr * 64 + lane] = p;

        // Next top with 2-deep forwarding (newest entry checked first).
        float sel;
        if (op == 0) {
            sel = (r0 == lastRow) ? lastVal
                : (r0 == lastRow2) ? lastVal2 : c0;
        } else if (op == 1) {
            sel = top;
        } else {
            int r2 = ptr + 1;
            sel = (r2 == lastRow) ? lastVal
                : (r2 == lastRow2) ? lastVal2 : c2;
        }
        if (op == 2) { lastRow2 = lastRow; lastVal2 = lastVal;
                       lastRow = ptr;      lastVal  = p; }

        int np = ptr + op - 1;
        ptr = (np < 0) ? 0 : np;
        top = sel;

        // ---- outputs: lanes 3..10 -> logits, lane 11 -> value ----
        if (lane >= 3 && lane <= 10) lgb[t * NA + (lane - 3)] = sv;
        if (lane == 11) values_out[(size_t)t * NB + b] = sv;
    }
    if (lane == 0) ptrs_out[b] = (float)ptr;
}

extern "C" void kernel_launch(void* const* d_in, const int* in_sizes, int n_in,
                              void* d_out, int out_size, void* d_ws, size_t ws_size,
                              hipStream_t stream) {
    const float* x        = (const float*)d_in[0];
    const float* stack_in = (const float*)d_in[1];
    const int*   ptrs_in  = (const int*)d_in[2];
    const float* W1 = (const float*)d_in[3];
    const float* b1 = (const float*)d_in[4];
    const float* W2 = (const float*)d_in[5];
    const float* b2 = (const float*)d_in[6];
    const float* Ws = (const float*)d_in[7];
    const float* bs = (const float*)d_in[8];
    const float* Wp = (const float*)d_in[9];
    const float* bp = (const float*)d_in[10];
    const float* Wv = (const float*)d_in[11];
    const float* bv = (const float*)d_in[12];

    float* out      = (float*)d_out;
    float* logits   = out;                 // 2097152
    float* values   = out + 2097152;       // 262144
    float* stack    = out + 2359296;       // 52690944
    float* ptrs_out = out + 55050240;      // 4096

    stacknet_kernel<<<NB, 64, 0, stream>>>(x, stack_in, ptrs_in,
                                           W1, b1, W2, b2, Ws, bs,
                                           Wp, bp, Wv, bv,
                                           logits, values, stack, ptrs_out);
}